// Round 1
// baseline (255.095 us; speedup 1.0000x reference)
//
#include <hip/hip_runtime.h>
#include <hip/hip_bf16.h>
#include <stdint.h>

// Problem constants
#define BQ 128    // batch
#define NJ 512    // input capsules j
#define DD 300    // input dim
#define NC 10     // num_capsule i
#define DC 64     // dim_capsule k
#define MM 640    // NC*DC
#define KP 320    // K padded (mult of 64)
#define RT 5      // routing iterations

typedef __attribute__((ext_vector_type(8))) short short8;
typedef __attribute__((ext_vector_type(4))) float f32x4;

// ---------------- cast / init kernels ----------------

__global__ void k_cast_x(const float* __restrict__ x, __hip_bfloat16* __restrict__ xb) {
    int g = blockIdx.x * 256 + threadIdx.x;      // 65536*40 groups
    int row = g / 40, cg2 = g - row * 40;
    const float* src = x + (size_t)row * DD + cg2 * 8;
    float4 a = make_float4(0.f, 0.f, 0.f, 0.f), b4 = a;
    if (cg2 < 37) { a = *(const float4*)src; b4 = *(const float4*)(src + 4); }
    else if (cg2 == 37) { a = *(const float4*)src; }
    union { ushort u[8]; uint4 v; } o;
    float f[8] = {a.x, a.y, a.z, a.w, b4.x, b4.y, b4.z, b4.w};
#pragma unroll
    for (int e = 0; e < 8; ++e) {
        __hip_bfloat16 hh = __float2bfloat16(f[e]);
        o.u[e] = *(ushort*)&hh;
    }
    *(uint4*)(xb + (size_t)row * KP + cg2 * 8) = o.v;
}

__global__ void k_cast_w(const float* __restrict__ w, __hip_bfloat16* __restrict__ wt) {
    int idx = blockIdx.x * 256 + threadIdx.x;
    int m = idx / KP, k = idx - m * KP;
    float v = (k < DD) ? w[(size_t)k * MM + m] : 0.f;
    wt[idx] = __float2bfloat16(v);
}

__global__ void k_zero(float4* __restrict__ p) {   // zero su (ws re-poisoned each call)
    p[blockIdx.x * 256 + threadIdx.x] = make_float4(0.f, 0.f, 0.f, 0.f);
}

// ---------------- MFMA GEMM + fused column-sum (pass-0 elimination) ----------------

__global__ __launch_bounds__(256)
void k_gemm(const __hip_bfloat16* __restrict__ A,
            const __hip_bfloat16* __restrict__ Bt,
            __hip_bfloat16* __restrict__ C,
            float* __restrict__ su) {              // su[b][640] = sum_j u[b,j,:]
    __shared__ __align__(16) __hip_bfloat16 As[128 * 64];
    __shared__ __align__(16) __hip_bfloat16 Bs[128 * 64];

    const int L  = blockIdx.x;
    const int n0 = ((L >> 3) % 5) * 128;
    const int m0 = ((L / 40) * 8 + (L & 7)) * 128;
    const int t  = threadIdx.x;
    const int w  = t >> 6, lane = t & 63;
    const int wrow = (w >> 1) * 64, wcol = (w & 1) * 64;
    const int quad = lane >> 4, r = lane & 15;

    f32x4 acc[4][4] = {};

    const int srow = t >> 3;
    const int sl   = (t & 7) ^ (srow & 7);
    const __hip_bfloat16* ag = A  + (size_t)(m0 + srow) * KP + sl * 8;
    const __hip_bfloat16* bg = Bt + (size_t)(n0 + srow) * KP + sl * 8;

    for (int kt = 0; kt < KP / 64; ++kt) {
        __syncthreads();
#pragma unroll
        for (int s = 0; s < 4; ++s) {
            __builtin_amdgcn_global_load_lds(
                (const __attribute__((address_space(1))) void*)(ag + (size_t)s * 32 * KP + kt * 64),
                (__attribute__((address_space(3))) void*)(&As[s * 2048 + t * 8]), 16, 0, 0);
            __builtin_amdgcn_global_load_lds(
                (const __attribute__((address_space(1))) void*)(bg + (size_t)s * 32 * KP + kt * 64),
                (__attribute__((address_space(3))) void*)(&Bs[s * 2048 + t * 8]), 16, 0, 0);
        }
        __syncthreads();

#pragma unroll
        for (int hh = 0; hh < 2; ++hh) {
            short8 af[4], bf[4];
#pragma unroll
            for (int mi = 0; mi < 4; ++mi) {
                int rho = wrow + mi * 16 + r;
                int p = (hh * 4 + quad) ^ (rho & 7);
                af[mi] = *(const short8*)&As[rho * 64 + p * 8];
            }
#pragma unroll
            for (int ni = 0; ni < 4; ++ni) {
                int rho = wcol + ni * 16 + r;
                int p = (hh * 4 + quad) ^ (rho & 7);
                bf[ni] = *(const short8*)&Bs[rho * 64 + p * 8];
            }
#pragma unroll
            for (int mi = 0; mi < 4; ++mi)
#pragma unroll
                for (int ni = 0; ni < 4; ++ni)
                    acc[mi][ni] = __builtin_amdgcn_mfma_f32_16x16x32_bf16(
                        af[mi], bf[ni], acc[mi][ni], 0, 0, 0);
        }
    }

#pragma unroll
    for (int mi = 0; mi < 4; ++mi)
#pragma unroll
        for (int ni = 0; ni < 4; ++ni) {
            int col = n0 + wcol + ni * 16 + r;
#pragma unroll
            for (int p = 0; p < 4; ++p) {
                int row = m0 + wrow + mi * 16 + quad * 4 + p;
                C[(size_t)row * MM + col] = __float2bfloat16(acc[mi][ni][p]);
            }
        }

    // fused column-sum: 128 rows of this block lie within one b (512 rows/b).
    float cs[4];
#pragma unroll
    for (int ni = 0; ni < 4; ++ni) {
        float s = 0.f;
#pragma unroll
        for (int mi = 0; mi < 4; ++mi)
#pragma unroll
            for (int p = 0; p < 4; ++p) s += acc[mi][ni][p];
        s += __shfl_xor(s, 16, 64);
        s += __shfl_xor(s, 32, 64);
        cs[ni] = s;
    }
    if (quad == 0) {
        int bb = m0 >> 9;
#pragma unroll
        for (int ni = 0; ni < 4; ++ni)
            atomicAdd(&su[(size_t)bb * MM + n0 + wcol + ni * 16 + r], cs[ni]);
    }
}

// ---------------- fused routing pass (barrier-free main loop) ----------------
// Block = (b, quarter q). 512 threads; thread t handles j-rows {q*128 + tt*16 + jd}
// for tt=0..7 with jd=t>>5, and k-pair kg=t&31 (k = 2kg, 2kg+1).
//
// v2 rationale: the old version staged each 16x640 u-tile in LDS and did the
// bl-reduction through a padded LDS matrix (3 barriers/tile, 160-thread serial
// reduce). But each u element is consumed by exactly ONE thread — LDS staging
// had zero reuse (pure overhead), and the direct global pattern is coalesced
// (lanes kg=0..31 read 128 contiguous bytes per (jd,i)). The bl reduce over kg
// is a 5-step __shfl_xor butterfly within the 32-lane half-wave. Main loop now
// has ZERO barriers; LDS 44.3KB -> 23KB.

__global__ __launch_bounds__(512)
void k_pass(const __hip_bfloat16* __restrict__ u, const float* __restrict__ pprev,
            float* __restrict__ pnext, int first) {
    __shared__ __align__(16) float outl[MM];            // squash(out_prev), 2560 B
    __shared__ __align__(16) float pored[8 * 32 * 20];  // epilogue transpose, 20480 B

    const int t   = threadIdx.x;
    const int blk = blockIdx.x;
    const int b   = blk >> 2, q = blk & 3;
    const int w   = t >> 6, lane = t & 63;
    const int jd  = t >> 5, kg = t & 31;

    // per-thread base: row (b, q*128 + jd), k-offset kg*2
    const ushort* ubase = (const ushort*)u
        + (size_t)(b * NJ + q * 128 + jd) * MM + kg * 2;

    // tile-0 prefetch (independent of prologue work)
    uint uv[10];
#pragma unroll
    for (int i = 0; i < 10; ++i) uv[i] = *(const uint*)(ubase + i * 64);

    // prologue: outl = squash(out_prev); waves 0..4, two i each
    if (w < 5) {
        float s0, s1;
        if (first) {                                 // out_0 from GEMM colsum
            s0 = 0.1f * pprev[(size_t)b * MM + w * 64 + lane];
            s1 = 0.1f * pprev[(size_t)b * MM + 320 + w * 64 + lane];
        } else {                                     // sum 4 quarter-partials
            const float* pp = pprev + (size_t)b * 4 * MM;
            s0 = 0.f; s1 = 0.f;
#pragma unroll
            for (int qq = 0; qq < 4; ++qq) {
                s0 += pp[qq * MM + w * 64 + lane];
                s1 += pp[qq * MM + 320 + w * 64 + lane];
            }
        }
        float q0 = s0 * s0, q1 = s1 * s1;
#pragma unroll
        for (int m = 32; m >= 1; m >>= 1) {
            q0 += __shfl_xor(q0, m, 64);
            q1 += __shfl_xor(q1, m, 64);
        }
        outl[w * 64 + lane]       = s0 * rsqrtf(q0 + 1e-7f);
        outl[320 + w * 64 + lane] = s1 * rsqrtf(q1 + 1e-7f);
    }
    __syncthreads();                                  // outl visible (only barrier before epilogue)

    // this thread's slice of outputs: outl[i*64 + 2kg, +1]
    float2 oo[10];
#pragma unroll
    for (int i = 0; i < 10; ++i) oo[i] = *(const float2*)(&outl[i * 64 + kg * 2]);

    float po[20];
#pragma unroll
    for (int e = 0; e < 20; ++e) po[e] = 0.f;

    for (int tt = 0; tt < 8; ++tt) {
        uint nv[10];
        if (tt < 7) {                                 // next tile's loads in flight
            const ushort* nrow = ubase + (size_t)(tt + 1) * 16 * MM;
#pragma unroll
            for (int i = 0; i < 10; ++i) nv[i] = *(const uint*)(nrow + i * 64);
        }

        // bl partial: dot with outputs over this thread's 2 k's
        float bl[10];
#pragma unroll
        for (int i = 0; i < 10; ++i) {
            float u0 = __uint_as_float(uv[i] << 16);
            float u1 = __uint_as_float(uv[i] & 0xffff0000u);
            bl[i] = u0 * oo[i].x + u1 * oo[i].y;
        }
        // butterfly over the 32-lane kg group (masks <=16 stay in the half-wave)
#pragma unroll
        for (int m = 1; m <= 16; m <<= 1)
#pragma unroll
            for (int i = 0; i < 10; ++i) bl[i] += __shfl_xor(bl[i], m, 64);

        // softmax over i (redundant across the 32 lanes sharing jd; no sync)
        float mx = -1e30f;
#pragma unroll
        for (int i = 0; i < 10; ++i) mx = fmaxf(mx, bl[i]);
        float ssum = 0.f;
#pragma unroll
        for (int i = 0; i < 10; ++i) { bl[i] = __expf(bl[i] - mx); ssum += bl[i]; }
        float inv = 1.f / ssum;

#pragma unroll
        for (int i = 0; i < 10; ++i) {
            float cc = bl[i] * inv;
            float u0 = __uint_as_float(uv[i] << 16);
            float u1 = __uint_as_float(uv[i] & 0xffff0000u);
            po[i * 2 + 0] += cc * u0;
            po[i * 2 + 1] += cc * u1;
        }

        if (tt < 7) {
#pragma unroll
            for (int i = 0; i < 10; ++i) uv[i] = nv[i];
        }
    }

    // epilogue: fold jd-halves in-register, then LDS transpose over 8 waves
#pragma unroll
    for (int e = 0; e < 20; ++e) po[e] += __shfl_xor(po[e], 32, 64);
    if (lane < 32) {
#pragma unroll
        for (int e = 0; e < 20; ++e) pored[(w * 32 + kg) * 20 + e] = po[e];
    }
    __syncthreads();
    for (int m = t; m < MM; m += 512) {
        int i = m >> 6, k = m & 63, kg2 = k >> 1, kd = k & 1;
        float s = 0.f;
#pragma unroll
        for (int ww = 0; ww < 8; ++ww) s += pored[(ww * 32 + kg2) * 20 + i * 2 + kd];
        pnext[(size_t)blk * MM + m] = s;
    }
}

// final squash: sum the 4 per-quarter partials, normalize each (b,i) 64-vector
__global__ __launch_bounds__(640)
void k_squash(const float* __restrict__ pbuf, float* __restrict__ dst) {
    int b = blockIdx.x, t = threadIdx.x;     // t = i*64 + k; wave = i
    float s = 0.f;
#pragma unroll
    for (int qq = 0; qq < 4; ++qq) s += pbuf[(size_t)(b * 4 + qq) * MM + t];
    float sq = s * s;
#pragma unroll
    for (int m = 32; m >= 1; m >>= 1) sq += __shfl_xor(sq, m, 64);
    dst[(size_t)b * MM + t] = s * rsqrtf(sq + 1e-7f);
}

// ---------------- launch ----------------

extern "C" void kernel_launch(void* const* d_in, const int* in_sizes, int n_in,
                              void* d_out, int out_size, void* d_ws, size_t ws_size,
                              hipStream_t stream) {
    const float* x = (const float*)d_in[0];   // [128,512,300]
    const float* W = (const float*)d_in[1];   // [1,300,640]
    float* out = (float*)d_out;               // [128,10,64]

    char* ws = (char*)d_ws;
    size_t o = 0;
    __hip_bfloat16* xb = (__hip_bfloat16*)(ws + o); o += (size_t)BQ * NJ * KP * 2;  // 41.9 MB
    __hip_bfloat16* wt = (__hip_bfloat16*)(ws + o); o += (size_t)MM * KP * 2;       // 0.4 MB
    __hip_bfloat16* u  = (__hip_bfloat16*)(ws + o); o += (size_t)BQ * NJ * MM * 2;  // 83.9 MB
    float* pb0 = (float*)(ws + o); o += (size_t)512 * MM * 4;                       // 1.3 MB
    float* pb1 = (float*)(ws + o); o += (size_t)512 * MM * 4;                       // 1.3 MB
    float* su  = (float*)(ws + o); o += (size_t)BQ * MM * 4;                        // 0.33 MB

    k_cast_x<<<(BQ * NJ * 40) / 256, 256, 0, stream>>>(x, xb);
    k_cast_w<<<(MM * KP) / 256, 256, 0, stream>>>(W, wt);
    k_zero<<<(BQ * MM) / (4 * 256), 256, 0, stream>>>((float4*)su);
    k_gemm<<<2560, 256, 0, stream>>>(xb, wt, u, su);

    // iterations 1..4 (iteration 0 folded into the GEMM colsum)
    k_pass<<<512, 512, 0, stream>>>(u, su,  pb0, 1);
    k_pass<<<512, 512, 0, stream>>>(u, pb0, pb1, 0);
    k_pass<<<512, 512, 0, stream>>>(u, pb1, pb0, 0);
    k_pass<<<512, 512, 0, stream>>>(u, pb0, pb1, 0);
    k_squash<<<BQ, 640, 0, stream>>>(pb1, out);
}